// Round 11
// baseline (955.336 us; speedup 1.0000x reference)
//
#include <hip/hip_runtime.h>

#define NB 2048
#define NT 2048
#define NH 16

#define OFF_IMP   1L
#define OFF_TRAIN (1L + (long)NB * NT)
#define OFF_EVALS (OFF_TRAIN + NB)
#define OFF_EMASK (OFF_EVALS + (long)NB * NT)

// ws layout: num_t[NT] | den_t[NT] | amt[NB*NT] (path A)  or  rep[NREP*NT] (path B)
#define WS_AMT_OFF 4096
#define NREP 64

typedef float f2 __attribute__((ext_vector_type(2)));

// ---------------- copies + workspace zeroing ----------------
__global__ void copy_zero_kernel(const float* __restrict__ evals,
                                 const float* __restrict__ emask,
                                 const float* __restrict__ is_train,
                                 float* __restrict__ out,
                                 float* __restrict__ ws,
                                 int n_zero) {
    long gid = (long)blockIdx.x * blockDim.x + threadIdx.x;
    if (gid < n_zero) ws[gid] = 0.0f;
    const long n1 = (long)NB * NT;
    const long total = NB + 2 * n1;
    const long stride = (long)gridDim.x * blockDim.x;
    for (long i = gid; i < total; i += stride) {
        if (i < NB)            out[OFF_TRAIN + i] = is_train[i];
        else if (i < NB + n1)  out[OFF_EVALS + (i - NB)] = evals[i - NB];
        else                   out[OFF_EMASK + (i - NB - n1)] = emask[i - NB - n1];
    }
}

// ---------------- LSTM scan: 16 lanes = 1 batch-PAIR, 8 batches per wave ----
// R9 structure per batch (verified, absmax 0.0078): lane (g,j) owns unit j and
// computes all 4 gate rows locally; h broadcast = ds_write + 4 ds_read_b128 in
// the group-private LDS row (same-wave DS order, no barrier). R11 change: each
// group runs TWO independent batches interleaved — stream B's issue fills
// stream A's dependency stalls (DS round trip + transcendental chain), which
// R10's counters showed were ~65% of the wall with 1 wave/SIMD. Weights are
// per-unit and batch-independent: both streams share the same 80 weight VGPRs.
// Per-batch arithmetic is bit-identical to R9.

#define L2E 1.4426950408889634f

#define DOT16(HH, W, RES) do {                                                 \
    f2 _a = HH[0] * W[0];                                                      \
    f2 _b = HH[4] * W[4];                                                      \
    _a = __builtin_elementwise_fma(HH[1], W[1], _a);                           \
    _b = __builtin_elementwise_fma(HH[5], W[5], _b);                           \
    _a = __builtin_elementwise_fma(HH[2], W[2], _a);                           \
    _b = __builtin_elementwise_fma(HH[6], W[6], _b);                           \
    _a = __builtin_elementwise_fma(HH[3], W[3], _a);                           \
    _b = __builtin_elementwise_fma(HH[7], W[7], _b);                           \
    RES = (_a.x + _a.y) + (_b.x + _b.y);                                       \
} while (0)

// Compute one batch-step up to ht (no DS ops) — R9 math, frozen.
#define STEPC(HH, CC, xx, mm, HT, XI, AI) do {                                 \
    float gI, gF, gG, gO, rr;                                                  \
    DOT16(HH, WI, gI); DOT16(HH, WF, gF); DOT16(HH, WG, gG);                   \
    DOT16(HH, WO, gO); DOT16(HH, WR, rr);                                      \
    const float xh  = brg + rr;                                                \
    const float dxm = (xx) - xh;                                               \
    const float xc  = fmaf((mm), dxm, xh);                                     \
    const float pI = fmaf(wxi0, xc, gI + fmaf(wxi1, (mm), bi));                \
    const float pF = fmaf(wxf0, xc, gF + fmaf(wxf1, (mm), bf));                \
    const float pG = fmaf(wxg0, xc, gG + fmaf(wxg1, (mm), bg));                \
    const float pO = fmaf(wxo0, xc, gO + fmaf(wxo1, (mm), bo));                \
    const float aI = __builtin_amdgcn_rcpf(1.0f + __builtin_amdgcn_exp2f(pI * (-L2E)));  \
    const float aF = __builtin_amdgcn_rcpf(1.0f + __builtin_amdgcn_exp2f(pF * (-L2E)));  \
    const float aG = fmaf(2.0f, __builtin_amdgcn_rcpf(1.0f + __builtin_amdgcn_exp2f(pG * (-2.0f * L2E))), -1.0f); \
    const float aO = __builtin_amdgcn_rcpf(1.0f + __builtin_amdgcn_exp2f(pO * (-L2E)));  \
    CC = fmaf(aF, CC, aI * aG);                                                \
    const float th = fmaf(2.0f, __builtin_amdgcn_rcpf(1.0f + __builtin_amdgcn_exp2f(CC * (-2.0f * L2E))), -1.0f); \
    HT = aO * th;                                                              \
    XI = xc;                                                                   \
    AI = fabsf(dxm) * (mm);                                                    \
} while (0)

// One fused step for both batches: compute A, compute B (interleaved by the
// scheduler), then one shared broadcast (2 writes, 8 reads, 1 lgkm wait).
#define STEP2(xa, ma, xb, mb, XIa, AIa, XIb, AIb) do {                         \
    float hta, htb;                                                            \
    STEPC(H2a, ca, xa, ma, hta, XIa, AIa);                                     \
    STEPC(H2b, cb, xb, mb, htb, XIb, AIb);                                     \
    hsh[hposA] = hta;                                                          \
    hsh[hposB] = htb;                                                          \
    {                                                                          \
        const float4 a0_ = *(const float4*)(hsh + baseA + 0);                  \
        const float4 a1_ = *(const float4*)(hsh + baseA + 4);                  \
        const float4 a2_ = *(const float4*)(hsh + baseA + 8);                  \
        const float4 a3_ = *(const float4*)(hsh + baseA + 12);                 \
        const float4 b0_ = *(const float4*)(hsh + baseB + 0);                  \
        const float4 b1_ = *(const float4*)(hsh + baseB + 4);                  \
        const float4 b2_ = *(const float4*)(hsh + baseB + 8);                  \
        const float4 b3_ = *(const float4*)(hsh + baseB + 12);                 \
        H2a[0] = (f2){a0_.x, a0_.y}; H2a[1] = (f2){a0_.z, a0_.w};              \
        H2a[2] = (f2){a1_.x, a1_.y}; H2a[3] = (f2){a1_.z, a1_.w};              \
        H2a[4] = (f2){a2_.x, a2_.y}; H2a[5] = (f2){a2_.z, a2_.w};              \
        H2a[6] = (f2){a3_.x, a3_.y}; H2a[7] = (f2){a3_.z, a3_.w};              \
        H2b[0] = (f2){b0_.x, b0_.y}; H2b[1] = (f2){b0_.z, b0_.w};              \
        H2b[2] = (f2){b1_.x, b1_.y}; H2b[3] = (f2){b1_.z, b1_.w};              \
        H2b[4] = (f2){b2_.x, b2_.y}; H2b[5] = (f2){b2_.z, b2_.w};              \
        H2b[6] = (f2){b3_.x, b3_.y}; H2b[7] = (f2){b3_.z, b3_.w};              \
    }                                                                          \
} while (0)

#define QUAD2(XA, MA, XB, MB, T4) do {                                         \
    float xiA0, xiA1, xiA2, xiA3, aiA0, aiA1, aiA2, aiA3;                      \
    float xiB0, xiB1, xiB2, xiB3, aiB0, aiB1, aiB2, aiB3;                      \
    STEP2(XA.x, MA.x, XB.x, MB.x, xiA0, aiA0, xiB0, aiB0);                     \
    STEP2(XA.y, MA.y, XB.y, MB.y, xiA1, aiA1, xiB1, aiB1);                     \
    STEP2(XA.z, MA.z, XB.z, MB.z, xiA2, aiA2, xiB2, aiB2);                     \
    STEP2(XA.w, MA.w, XB.w, MB.w, xiA3, aiA3, xiB3, aiB3);                     \
    if (ATOMIC) {                                                              \
        if (j == 0) {                                                          \
            atomicAdd(ab_a + (T4) + 0, aiA0); atomicAdd(ab_a + (T4) + 1, aiA1);\
            atomicAdd(ab_a + (T4) + 2, aiA2); atomicAdd(ab_a + (T4) + 3, aiA3);\
        }                                                                      \
        if (j == 8) {                                                          \
            atomicAdd(ab_b + (T4) + 0, aiB0); atomicAdd(ab_b + (T4) + 1, aiB1);\
            atomicAdd(ab_b + (T4) + 2, aiB2); atomicAdd(ab_b + (T4) + 3, aiB3);\
        }                                                                      \
        if (j < 4) {                                                           \
            const float sx = (j == 1) ? xiA1 : (j == 2) ? xiA2 : (j == 3) ? xiA3 : xiA0; \
            ib_a[(T4) + j] = sx;                                               \
        } else if (j >= 8 && j < 12) {                                         \
            const int jq = j & 3;                                              \
            const float sx = (jq == 1) ? xiB1 : (jq == 2) ? xiB2 : (jq == 3) ? xiB3 : xiB0; \
            ib_b[(T4) + jq] = sx;                                              \
        }                                                                      \
    } else {                                                                   \
        const int jq = j & 3;                                                  \
        const float sxa = (jq == 1) ? xiA1 : (jq == 2) ? xiA2 : (jq == 3) ? xiA3 : xiA0; \
        const float saa = (jq == 1) ? aiA1 : (jq == 2) ? aiA2 : (jq == 3) ? aiA3 : aiA0; \
        const float sxb = (jq == 1) ? xiB1 : (jq == 2) ? xiB2 : (jq == 3) ? xiB3 : xiB0; \
        const float sab = (jq == 1) ? aiB1 : (jq == 2) ? aiB2 : (jq == 3) ? aiB3 : aiB0; \
        const float vA = ((j >> 2) & 1) ? saa : sxa;                           \
        const float vB = ((j >> 2) & 1) ? sab : sxb;                           \
        pst[T4] = (j >= 8) ? vB : vA;                                          \
    }                                                                          \
} while (0)

template <int ATOMIC>
__global__ __launch_bounds__(64, 1)
void lstm_kernel(const float* __restrict__ values,
                 const float* __restrict__ masks,
                 const float* __restrict__ W_ih,
                 const float* __restrict__ W_hh,
                 const float* __restrict__ b_ih,
                 const float* __restrict__ b_hh,
                 const float* __restrict__ W_reg,
                 const float* __restrict__ b_reg,
                 float* __restrict__ imp,   // out + OFF_IMP
                 float* __restrict__ amt) { // A: amt[NB*NT]; B: rep[NREP*NT]
    const int lane = threadIdx.x;          // 0..63
    const int g = lane >> 4;               // group (batch-pair slot) in wave
    const int j = lane & 15;               // hidden unit
    const long bA = (long)blockIdx.x * 8 + g * 2;
    const long bB = bA + 1;

    // Per-lane weights (shared by both streams): 4 W_hh gate rows for unit j
    // + W_reg, packed as f2 pairs (w_k, w_{k+4}) matching the permuted LDS h.
    f2 WI[8], WF[8], WG[8], WO[8], WR[8];
    {
        const float* rI = W_hh + (0 * NH + j) * NH;
        const float* rF = W_hh + (1 * NH + j) * NH;
        const float* rG = W_hh + (2 * NH + j) * NH;
        const float* rO = W_hh + (3 * NH + j) * NH;
#pragma unroll
        for (int k = 0; k < 4; ++k) {
            WI[k] = (f2){rI[k], rI[k + 4]};  WI[4 + k] = (f2){rI[8 + k], rI[12 + k]};
            WF[k] = (f2){rF[k], rF[k + 4]};  WF[4 + k] = (f2){rF[8 + k], rF[12 + k]};
            WG[k] = (f2){rG[k], rG[k + 4]};  WG[4 + k] = (f2){rG[8 + k], rG[12 + k]};
            WO[k] = (f2){rO[k], rO[k + 4]};  WO[4 + k] = (f2){rO[8 + k], rO[12 + k]};
            WR[k] = (f2){W_reg[k], W_reg[k + 4]};
            WR[4 + k] = (f2){W_reg[8 + k], W_reg[12 + k]};
        }
    }
    const float wxi0 = W_ih[(0 * NH + j) * 2 + 0], wxi1 = W_ih[(0 * NH + j) * 2 + 1];
    const float wxf0 = W_ih[(1 * NH + j) * 2 + 0], wxf1 = W_ih[(1 * NH + j) * 2 + 1];
    const float wxg0 = W_ih[(2 * NH + j) * 2 + 0], wxg1 = W_ih[(2 * NH + j) * 2 + 1];
    const float wxo0 = W_ih[(3 * NH + j) * 2 + 0], wxo1 = W_ih[(3 * NH + j) * 2 + 1];
    const float bi = b_ih[0 * NH + j] + b_hh[0 * NH + j];
    const float bf = b_ih[1 * NH + j] + b_hh[1 * NH + j];
    const float bg = b_ih[2 * NH + j] + b_hh[2 * NH + j];
    const float bo = b_ih[3 * NH + j] + b_hh[3 * NH + j];
    const float brg = b_reg[0];

    f2 H2a[8], H2b[8];
#pragma unroll
    for (int k = 0; k < 8; ++k) { H2a[k] = (f2){0.0f, 0.0f}; H2b[k] = (f2){0.0f, 0.0f}; }
    float ca = 0.0f, cb = 0.0f;

    // Permuted h layout per 16-row: [h0,h4,h1,h5,h2,h6,h3,h7, h8,h12,...]
    __shared__ __align__(16) float hsh[128];
    const int jj = j & 7;
    const int perm = ((j >> 3) << 3) + ((jj & 3) << 1) + (jj >> 2);
    const int baseA = g << 5;              // row 2g
    const int baseB = baseA + 16;          // row 2g+1
    const int hposA = baseA + perm;
    const int hposB = baseB + perm;

    const float* va  = values + bA * NT;
    const float* ma_ = masks + bA * NT;
    const float* vb_ = values + bB * NT;
    const float* mb_ = masks + bB * NT;
    float* ib_a = imp + bA * NT;
    float* ib_b = imp + bB * NT;
    float* ab_a = ATOMIC ? (amt + (long)(bA & (NREP - 1)) * NT) : (amt + bA * NT);
    float* ab_b = ATOMIC ? (amt + (long)(bB & (NREP - 1)) * NT) : (amt + bB * NT);
    // store role: j0-3 xcA, j4-7 avA, j8-11 xcB, j12-15 avB (group-uniform vals)
    float* ibx = (j >= 8) ? ib_b : ib_a;
    float* abx = (j >= 8) ? ab_b : ab_a;
    float* pst = (((j >> 2) & 1) ? abx : ibx) + (j & 3);

    // 2 prefetch buffers per stream, 8-step unrolled body
    float4 xA0 = *(const float4*)(va + 0),  xA1 = *(const float4*)(va + 4);
    float4 mA0 = *(const float4*)(ma_ + 0), mA1 = *(const float4*)(ma_ + 4);
    float4 xB0 = *(const float4*)(vb_ + 0), xB1 = *(const float4*)(vb_ + 4);
    float4 mB0 = *(const float4*)(mb_ + 0), mB1 = *(const float4*)(mb_ + 4);

    for (int t = 0; t < NT; t += 8) {
        QUAD2(xA0, mA0, xB0, mB0, t);
        {
            const int tn = (t + 8) & (NT - 1);   // wraps harmlessly on last iter
            xA0 = *(const float4*)(va + tn);  mA0 = *(const float4*)(ma_ + tn);
            xB0 = *(const float4*)(vb_ + tn); mB0 = *(const float4*)(mb_ + tn);
        }
        QUAD2(xA1, mA1, xB1, mB1, t + 4);
        {
            const int tn = (t + 12) & (NT - 1);
            xA1 = *(const float4*)(va + tn);  mA1 = *(const float4*)(ma_ + tn);
            xB1 = *(const float4*)(vb_ + tn); mB1 = *(const float4*)(mb_ + tn);
        }
    }
}

// ---------------- column-sum reduce: num_t / den_t ----------------
template <int ATOMIC>
__global__ void reduce_kernel(const float* __restrict__ masks,
                              const float* __restrict__ amt,
                              float* __restrict__ num_t,
                              float* __restrict__ den_t) {
    const int t = blockIdx.x * 256 + threadIdx.x;
    const int b0 = blockIdx.y * 32;
    float sd = 0.0f;
    for (int bb = b0; bb < b0 + 32; ++bb) sd += masks[(long)bb * NT + t];
    atomicAdd(den_t + t, sd);
    if (!ATOMIC) {
        float sn = 0.0f;
        for (int bb = b0; bb < b0 + 32; ++bb) sn += amt[(long)bb * NT + t];
        atomicAdd(num_t + t, sn);
    } else if (blockIdx.y == 0) {
        float sn = 0.0f;
        for (int r = 0; r < NREP; ++r) sn += amt[(long)r * NT + t];
        num_t[t] = sn;  // single writer
    }
}

// ---------------- loss finalize ----------------
__global__ void loss_kernel(const float* __restrict__ num_t, const float* __restrict__ den_t,
                            float* __restrict__ out) {
    const int tid = threadIdx.x;
    float s = 0.0f;
    for (int t = tid; t < NT; t += 256) s += num_t[t] / (den_t[t] + 1e-5f);
#pragma unroll
    for (int off = 32; off > 0; off >>= 1) s += __shfl_down(s, off, 64);
    __shared__ float red[4];
    if ((tid & 63) == 0) red[tid >> 6] = s;
    __syncthreads();
    if (tid == 0) out[0] = (red[0] + red[1] + red[2] + red[3]) / (float)NT;
}

extern "C" void kernel_launch(void* const* d_in, const int* in_sizes, int n_in,
                              void* d_out, int out_size, void* d_ws, size_t ws_size,
                              hipStream_t stream) {
    const float* values  = (const float*)d_in[0];
    const float* masks   = (const float*)d_in[1];
    const float* evals   = (const float*)d_in[2];
    const float* emask   = (const float*)d_in[3];
    const float* istrain = (const float*)d_in[4];
    const float* W_ih    = (const float*)d_in[5];
    const float* W_hh    = (const float*)d_in[6];
    const float* b_ih    = (const float*)d_in[7];
    const float* b_hh    = (const float*)d_in[8];
    const float* W_reg   = (const float*)d_in[9];
    const float* b_reg   = (const float*)d_in[10];

    float* out = (float*)d_out;
    float* ws = (float*)d_ws;
    float* num_t = ws;
    float* den_t = ws + NT;
    float* amt = ws + WS_AMT_OFF;

    const bool pathA = ws_size >= (size_t)(WS_AMT_OFF + (long)NB * NT) * 4;

    if (pathA) {
        copy_zero_kernel<<<1024, 256, 0, stream>>>(evals, emask, istrain, out, ws, WS_AMT_OFF);
        lstm_kernel<0><<<NB / 8, 64, 0, stream>>>(values, masks, W_ih, W_hh, b_ih, b_hh,
                                                  W_reg, b_reg, out + OFF_IMP, amt);
        reduce_kernel<0><<<dim3(NT / 256, 64), 256, 0, stream>>>(masks, amt, num_t, den_t);
    } else {
        copy_zero_kernel<<<1024, 256, 0, stream>>>(evals, emask, istrain, out, ws,
                                                   WS_AMT_OFF + NREP * NT);
        lstm_kernel<1><<<NB / 8, 64, 0, stream>>>(values, masks, W_ih, W_hh, b_ih, b_hh,
                                                  W_reg, b_reg, out + OFF_IMP, amt);
        reduce_kernel<1><<<dim3(NT / 256, 64), 256, 0, stream>>>(masks, amt, num_t, den_t);
    }
    loss_kernel<<<1, 256, 0, stream>>>(num_t, den_t, out);
}

// Round 12
// 552.190 us; speedup vs baseline: 1.7301x; 1.7301x over previous
//
#include <hip/hip_runtime.h>

#define NB 2048
#define NT 2048
#define NH 16

#define OFF_IMP   1L
#define OFF_TRAIN (1L + (long)NB * NT)
#define OFF_EVALS (OFF_TRAIN + NB)
#define OFF_EMASK (OFF_EVALS + (long)NB * NT)

// ws layout: num_t[NT] | den_t[NT] | amt[NB*NT] (path A)  or  rep[NREP*NT] (path B)
#define WS_AMT_OFF 4096
#define NREP 64

typedef float f2 __attribute__((ext_vector_type(2)));

// ---------------- copies + workspace zeroing ----------------
__global__ void copy_zero_kernel(const float* __restrict__ evals,
                                 const float* __restrict__ emask,
                                 const float* __restrict__ is_train,
                                 float* __restrict__ out,
                                 float* __restrict__ ws,
                                 int n_zero) {
    long gid = (long)blockIdx.x * blockDim.x + threadIdx.x;
    if (gid < n_zero) ws[gid] = 0.0f;
    const long n1 = (long)NB * NT;
    const long total = NB + 2 * n1;
    const long stride = (long)gridDim.x * blockDim.x;
    for (long i = gid; i < total; i += stride) {
        if (i < NB)            out[OFF_TRAIN + i] = is_train[i];
        else if (i < NB + n1)  out[OFF_EVALS + (i - NB)] = evals[i - NB];
        else                   out[OFF_EMASK + (i - NB - n1)] = emask[i - NB - n1];
    }
}

// ---------------- LSTM scan: 16 lanes = 1 batch, 4 batches per wave --------
// R9 structure and BIT-IDENTICAL math (verified absmax 0.0078125).
// R12 changes are pressure-only:
//  - 8-step unrolled body (was 16) so the register allocator stops
//    rematerializing the ~45 weight loads inside the loop (R9/R10 showed
//    VGPR=80/92 against >=90 live weight registers).
//  - W_reg/b_reg held as wave-uniform scalars (readfirstlane, bit-exact);
//    the W_reg dot uses scalar fma chains r0..r3 whose association equals
//    R9's DOT16 lanes exactly: r0=h0..h3, r1=h4..h7, r2=h8..h11, r3=h12..h15,
//    xh = brg + ((r0+r1)+(r2+r3)).

#define L2E 1.4426950408889634f

__device__ __forceinline__ float rfl(float v) {
    return __int_as_float(__builtin_amdgcn_readfirstlane(__float_as_int(v)));
}

#define DOT16(W, RES) do {                                                     \
    f2 _a = H2[0] * W[0];                                                      \
    f2 _b = H2[4] * W[4];                                                      \
    _a = __builtin_elementwise_fma(H2[1], W[1], _a);                           \
    _b = __builtin_elementwise_fma(H2[5], W[5], _b);                           \
    _a = __builtin_elementwise_fma(H2[2], W[2], _a);                           \
    _b = __builtin_elementwise_fma(H2[6], W[6], _b);                           \
    _a = __builtin_elementwise_fma(H2[3], W[3], _a);                           \
    _b = __builtin_elementwise_fma(H2[7], W[7], _b);                           \
    RES = (_a.x + _a.y) + (_b.x + _b.y);                                       \
} while (0)

#define STEP(xx, mm, XI, AI) do {                                              \
    float gI, gF, gG, gO;                                                      \
    DOT16(WI, gI); DOT16(WF, gF); DOT16(WG, gG); DOT16(WO, gO);                \
    float r0 = H2[0].x * wr0;                                                  \
    r0 = fmaf(H2[1].x, wr1, r0); r0 = fmaf(H2[2].x, wr2, r0);                  \
    r0 = fmaf(H2[3].x, wr3, r0);                                               \
    float r1 = H2[0].y * wr4;                                                  \
    r1 = fmaf(H2[1].y, wr5, r1); r1 = fmaf(H2[2].y, wr6, r1);                  \
    r1 = fmaf(H2[3].y, wr7, r1);                                               \
    float r2 = H2[4].x * wr8;                                                  \
    r2 = fmaf(H2[5].x, wr9, r2); r2 = fmaf(H2[6].x, wr10, r2);                 \
    r2 = fmaf(H2[7].x, wr11, r2);                                              \
    float r3 = H2[4].y * wr12;                                                 \
    r3 = fmaf(H2[5].y, wr13, r3); r3 = fmaf(H2[6].y, wr14, r3);                \
    r3 = fmaf(H2[7].y, wr15, r3);                                              \
    const float xh  = brg + ((r0 + r1) + (r2 + r3));                           \
    const float dxm = (xx) - xh;                                               \
    const float xc  = fmaf((mm), dxm, xh);                                     \
    const float pI = fmaf(wxi0, xc, gI + fmaf(wxi1, (mm), bi));                \
    const float pF = fmaf(wxf0, xc, gF + fmaf(wxf1, (mm), bf));                \
    const float pG = fmaf(wxg0, xc, gG + fmaf(wxg1, (mm), bg));                \
    const float pO = fmaf(wxo0, xc, gO + fmaf(wxo1, (mm), bo));                \
    const float aI = __builtin_amdgcn_rcpf(1.0f + __builtin_amdgcn_exp2f(pI * (-L2E)));  \
    const float aF = __builtin_amdgcn_rcpf(1.0f + __builtin_amdgcn_exp2f(pF * (-L2E)));  \
    const float aG = fmaf(2.0f, __builtin_amdgcn_rcpf(1.0f + __builtin_amdgcn_exp2f(pG * (-2.0f * L2E))), -1.0f); \
    const float aO = __builtin_amdgcn_rcpf(1.0f + __builtin_amdgcn_exp2f(pO * (-L2E)));  \
    c = fmaf(aF, c, aI * aG);                                                  \
    const float th = fmaf(2.0f, __builtin_amdgcn_rcpf(1.0f + __builtin_amdgcn_exp2f(c * (-2.0f * L2E))), -1.0f); \
    const float ht = aO * th;                                                  \
    hsh[hpos] = ht;                                                            \
    {                                                                          \
        const float4 h0_ = *(const float4*)(hsh + (g << 4) + 0);               \
        const float4 h1_ = *(const float4*)(hsh + (g << 4) + 4);               \
        const float4 h2_ = *(const float4*)(hsh + (g << 4) + 8);               \
        const float4 h3_ = *(const float4*)(hsh + (g << 4) + 12);              \
        H2[0] = (f2){h0_.x, h0_.y}; H2[1] = (f2){h0_.z, h0_.w};                \
        H2[2] = (f2){h1_.x, h1_.y}; H2[3] = (f2){h1_.z, h1_.w};                \
        H2[4] = (f2){h2_.x, h2_.y}; H2[5] = (f2){h2_.z, h2_.w};                \
        H2[6] = (f2){h3_.x, h3_.y}; H2[7] = (f2){h3_.z, h3_.w};                \
    }                                                                          \
    XI = xc; AI = fabsf(dxm) * (mm);                                           \
} while (0)

#define QUAD(XV, MV, T4) do {                                                  \
    float xi0, xi1, xi2, xi3, ai0, ai1, ai2, ai3;                              \
    STEP(XV.x, MV.x, xi0, ai0); STEP(XV.y, MV.y, xi1, ai1);                    \
    STEP(XV.z, MV.z, xi2, ai2); STEP(XV.w, MV.w, xi3, ai3);                    \
    if (ATOMIC) {                                                              \
        if (j == 0) {                                                          \
            atomicAdd(ab + (T4) + 0, ai0); atomicAdd(ab + (T4) + 1, ai1);      \
            atomicAdd(ab + (T4) + 2, ai2); atomicAdd(ab + (T4) + 3, ai3);      \
        }                                                                      \
        if (j < 4) {                                                           \
            const float sx = (j == 1) ? xi1 : (j == 2) ? xi2 : (j == 3) ? xi3 : xi0; \
            ib[(T4) + j] = sx;                                                 \
        }                                                                      \
    } else {                                                                   \
        const int jq = j & 3;                                                  \
        const float sx = (jq == 1) ? xi1 : (jq == 2) ? xi2 : (jq == 3) ? xi3 : xi0; \
        const float sa = (jq == 1) ? ai1 : (jq == 2) ? ai2 : (jq == 3) ? ai3 : ai0; \
        if (j < 8) pst[T4] = (j < 4) ? sx : sa;                                \
    }                                                                          \
} while (0)

template <int ATOMIC>
__global__ __launch_bounds__(64, 1)
void lstm_kernel(const float* __restrict__ values,
                 const float* __restrict__ masks,
                 const float* __restrict__ W_ih,
                 const float* __restrict__ W_hh,
                 const float* __restrict__ b_ih,
                 const float* __restrict__ b_hh,
                 const float* __restrict__ W_reg,
                 const float* __restrict__ b_reg,
                 float* __restrict__ imp,   // out + OFF_IMP
                 float* __restrict__ amt) { // A: amt[NB*NT]; B: rep[NREP*NT]
    const int lane = threadIdx.x;          // 0..63
    const int g = lane >> 4;               // batch slot within wave
    const int j = lane & 15;               // hidden unit
    const long b = (long)blockIdx.x * 4 + g;

    // Per-lane W_hh gate rows for unit j, packed as f2 pairs (w_k, w_{k+4})
    // matching the permuted LDS h layout.
    f2 WI[8], WF[8], WG[8], WO[8];
    {
        const float* rI = W_hh + (0 * NH + j) * NH;
        const float* rF = W_hh + (1 * NH + j) * NH;
        const float* rG = W_hh + (2 * NH + j) * NH;
        const float* rO = W_hh + (3 * NH + j) * NH;
#pragma unroll
        for (int k = 0; k < 4; ++k) {
            WI[k] = (f2){rI[k], rI[k + 4]};  WI[4 + k] = (f2){rI[8 + k], rI[12 + k]};
            WF[k] = (f2){rF[k], rF[k + 4]};  WF[4 + k] = (f2){rF[8 + k], rF[12 + k]};
            WG[k] = (f2){rG[k], rG[k + 4]};  WG[4 + k] = (f2){rG[8 + k], rG[12 + k]};
            WO[k] = (f2){rO[k], rO[k + 4]};  WO[4 + k] = (f2){rO[8 + k], rO[12 + k]};
        }
    }
    // W_reg + b_reg are identical across all lanes -> wave-uniform scalars
    // (readfirstlane is bit-exact; frees 18 VGPRs and shrinks the remat set).
    const float wr0 = rfl(W_reg[0]),  wr1 = rfl(W_reg[1]);
    const float wr2 = rfl(W_reg[2]),  wr3 = rfl(W_reg[3]);
    const float wr4 = rfl(W_reg[4]),  wr5 = rfl(W_reg[5]);
    const float wr6 = rfl(W_reg[6]),  wr7 = rfl(W_reg[7]);
    const float wr8 = rfl(W_reg[8]),  wr9 = rfl(W_reg[9]);
    const float wr10 = rfl(W_reg[10]), wr11 = rfl(W_reg[11]);
    const float wr12 = rfl(W_reg[12]), wr13 = rfl(W_reg[13]);
    const float wr14 = rfl(W_reg[14]), wr15 = rfl(W_reg[15]);
    const float brg = rfl(b_reg[0]);

    const float wxi0 = W_ih[(0 * NH + j) * 2 + 0], wxi1 = W_ih[(0 * NH + j) * 2 + 1];
    const float wxf0 = W_ih[(1 * NH + j) * 2 + 0], wxf1 = W_ih[(1 * NH + j) * 2 + 1];
    const float wxg0 = W_ih[(2 * NH + j) * 2 + 0], wxg1 = W_ih[(2 * NH + j) * 2 + 1];
    const float wxo0 = W_ih[(3 * NH + j) * 2 + 0], wxo1 = W_ih[(3 * NH + j) * 2 + 1];
    const float bi = b_ih[0 * NH + j] + b_hh[0 * NH + j];
    const float bf = b_ih[1 * NH + j] + b_hh[1 * NH + j];
    const float bg = b_ih[2 * NH + j] + b_hh[2 * NH + j];
    const float bo = b_ih[3 * NH + j] + b_hh[3 * NH + j];

    f2 H2[8];
#pragma unroll
    for (int k = 0; k < 8; ++k) H2[k] = (f2){0.0f, 0.0f};
    float c = 0.0f;

    // Permuted h store position: layout [h0,h4,h1,h5,h2,h6,h3,h7, h8,h12,...]
    // rows at 64B stride (g<<4 floats) — R9-verified conflict-free.
    __shared__ __align__(16) float hsh[64];
    const int jj = j & 7;
    const int hpos = (g << 4) + ((j >> 3) << 3) + ((jj & 3) << 1) + (jj >> 2);

    const float* vb = values + b * NT;
    const float* mb = masks + b * NT;
    float* ib = imp + b * NT;
    float* ab = ATOMIC ? (amt + (long)(b & (NREP - 1)) * NT) : (amt + b * NT);
    // lanes j=0..3 -> imputation col jq, lanes j=4..7 -> loss col jq
    float* pst = ((j < 4) ? ib : ab) + (j & 3);

    // 2 prefetch buffers, 8-step body, zero rotation movs: each buffer is
    // reloaded (distance 8 steps) immediately after the QUAD that consumes it.
    float4 xA = *(const float4*)(vb + 0), mA = *(const float4*)(mb + 0);
    float4 xB = *(const float4*)(vb + 4), mB = *(const float4*)(mb + 4);

    for (int t = 0; t < NT; t += 8) {
        QUAD(xA, mA, t);
        {
            const int tn = (t + 8) & (NT - 1);   // wraps harmlessly on last iter
            xA = *(const float4*)(vb + tn);
            mA = *(const float4*)(mb + tn);
        }
        QUAD(xB, mB, t + 4);
        {
            const int tn = (t + 12) & (NT - 1);
            xB = *(const float4*)(vb + tn);
            mB = *(const float4*)(mb + tn);
        }
    }
}

// ---------------- column-sum reduce: num_t / den_t ----------------
template <int ATOMIC>
__global__ void reduce_kernel(const float* __restrict__ masks,
                              const float* __restrict__ amt,
                              float* __restrict__ num_t,
                              float* __restrict__ den_t) {
    const int t = blockIdx.x * 256 + threadIdx.x;
    const int b0 = blockIdx.y * 32;
    float sd = 0.0f;
    for (int bb = b0; bb < b0 + 32; ++bb) sd += masks[(long)bb * NT + t];
    atomicAdd(den_t + t, sd);
    if (!ATOMIC) {
        float sn = 0.0f;
        for (int bb = b0; bb < b0 + 32; ++bb) sn += amt[(long)bb * NT + t];
        atomicAdd(num_t + t, sn);
    } else if (blockIdx.y == 0) {
        float sn = 0.0f;
        for (int r = 0; r < NREP; ++r) sn += amt[(long)r * NT + t];
        num_t[t] = sn;  // single writer
    }
}

// ---------------- loss finalize ----------------
__global__ void loss_kernel(const float* __restrict__ num_t, const float* __restrict__ den_t,
                            float* __restrict__ out) {
    const int tid = threadIdx.x;
    float s = 0.0f;
    for (int t = tid; t < NT; t += 256) s += num_t[t] / (den_t[t] + 1e-5f);
#pragma unroll
    for (int off = 32; off > 0; off >>= 1) s += __shfl_down(s, off, 64);
    __shared__ float red[4];
    if ((tid & 63) == 0) red[tid >> 6] = s;
    __syncthreads();
    if (tid == 0) out[0] = (red[0] + red[1] + red[2] + red[3]) / (float)NT;
}

extern "C" void kernel_launch(void* const* d_in, const int* in_sizes, int n_in,
                              void* d_out, int out_size, void* d_ws, size_t ws_size,
                              hipStream_t stream) {
    const float* values  = (const float*)d_in[0];
    const float* masks   = (const float*)d_in[1];
    const float* evals   = (const float*)d_in[2];
    const float* emask   = (const float*)d_in[3];
    const float* istrain = (const float*)d_in[4];
    const float* W_ih    = (const float*)d_in[5];
    const float* W_hh    = (const float*)d_in[6];
    const float* b_ih    = (const float*)d_in[7];
    const float* b_hh    = (const float*)d_in[8];
    const float* W_reg   = (const float*)d_in[9];
    const float* b_reg   = (const float*)d_in[10];

    float* out = (float*)d_out;
    float* ws = (float*)d_ws;
    float* num_t = ws;
    float* den_t = ws + NT;
    float* amt = ws + WS_AMT_OFF;

    const bool pathA = ws_size >= (size_t)(WS_AMT_OFF + (long)NB * NT) * 4;

    if (pathA) {
        copy_zero_kernel<<<1024, 256, 0, stream>>>(evals, emask, istrain, out, ws, WS_AMT_OFF);
        lstm_kernel<0><<<NB / 4, 64, 0, stream>>>(values, masks, W_ih, W_hh, b_ih, b_hh,
                                                  W_reg, b_reg, out + OFF_IMP, amt);
        reduce_kernel<0><<<dim3(NT / 256, 64), 256, 0, stream>>>(masks, amt, num_t, den_t);
    } else {
        copy_zero_kernel<<<1024, 256, 0, stream>>>(evals, emask, istrain, out, ws,
                                                   WS_AMT_OFF + NREP * NT);
        lstm_kernel<1><<<NB / 4, 64, 0, stream>>>(values, masks, W_ih, W_hh, b_ih, b_hh,
                                                  W_reg, b_reg, out + OFF_IMP, amt);
        reduce_kernel<1><<<dim3(NT / 256, 64), 256, 0, stream>>>(masks, amt, num_t, den_t);
    }
    loss_kernel<<<1, 256, 0, stream>>>(num_t, den_t, out);
}